// Round 19
// baseline (8624.839 us; speedup 1.0000x reference)
//
#include <hip/hip_runtime.h>
#include <hip/hip_bf16.h>
#include <hip/hip_fp16.h>
#include <math.h>

// Problem constants
constexpr int L    = 1024;
constexpr int B    = 64;
constexpr int H    = 512;
constexpr int ED   = 512;
constexpr int PSSM = 21;
constexpr int DIN  = ED + PSSM;    // 533
constexpr int LU   = 60;
constexpr int HB   = H * B;        // 32768 shorts (64 KB) per timestep slab
constexpr int NWG_DIR = 32;        // fat MFMA workgroups per direction
constexpr int UPW  = 16;           // hidden units per WG

typedef __attribute__((ext_vector_type(8))) _Float16 half8;    // MFMA fp16 frag
typedef __attribute__((ext_vector_type(4))) float f32x4;       // MFMA acc frag

__device__ __forceinline__ float fast_tanh(float x) {
    // tanh(x) = 1 - 2/(exp(2x)+1); exp overflow -> 1, underflow -> -1 (no NaN)
    float e = __expf(2.f * x);
    return 1.f - 2.f / (e + 1.f);
}

// ---------------------------------------------------------------------------
// P0: E2[dir][sym][col] = embed[sym] . Wih_dir[col][0:512] + bih[col]+bhh[col]
// ---------------------------------------------------------------------------
__global__ __launch_bounds__(256) void prep_e2(
    const float* __restrict__ Wih_f, const float* __restrict__ Wih_b,
    const float* __restrict__ bih_f, const float* __restrict__ bhh_f,
    const float* __restrict__ bih_b, const float* __restrict__ bhh_b,
    const float* __restrict__ embed, float* __restrict__ E2)
{
    int idx  = blockIdx.x * 256 + threadIdx.x;   // 0 .. 81919
    int col  = idx & 2047;
    int rest = idx >> 11;
    int s    = rest % 20;
    int dir  = rest / 20;
    const float* W  = dir ? Wih_b : Wih_f;
    const float* er = embed + (size_t)s * ED;
    const float* wr = W + (size_t)col * DIN;
    float a = 0.f;
    #pragma unroll 8
    for (int k = 0; k < ED; ++k) a = fmaf(er[k], wr[k], a);
    a += (dir ? bih_b : bih_f)[col] + (dir ? bhh_b : bhh_f)[col];
    E2[idx] = a;
}

// ---------------------------------------------------------------------------
// P1: split Whh into fp16 hi/lo pair (2-product split, w err ~2^-22).
// R13 PROVED single-product fp16 diverges 75x over threshold -> 2 required.
// ---------------------------------------------------------------------------
__global__ __launch_bounds__(256) void prep_whh(
    const float* __restrict__ Whh_f, const float* __restrict__ Whh_b,
    unsigned short* __restrict__ hi, unsigned short* __restrict__ lo)
{
    int idx = blockIdx.x * 256 + threadIdx.x;    // 0 .. 2*2048*512-1
    const int NPD = 2048 * 512;
    float w = (idx < NPD) ? Whh_f[idx] : Whh_b[idx - NPD];
    __half h = __float2half_rn(w);
    __half l2 = __float2half_rn(w - __half2float(h));
    hi[idx] = __half_as_ushort(h);
    lo[idx] = __half_as_ushort(l2);
}

// ---------------------------------------------------------------------------
// K1: persistent bidirectional LSTM, MFMA fp16. 64 WGs (32/dir), 1 WG/CU.
// R17/R18: per-chunk poll||compute pipeline, NAMED-REGISTER edition.
//   R16 (NaN) used af[16] + per-chunk while loops inside `#pragma unroll`;
//   if the unroll is declined, af[] becomes runtime-indexed -> scratch
//   (rule 20) -> spill copies of asm-load outputs execute before vmcnt(0)
//   (the R6/R8 hazard) -> stale sentinel forever -> dead-man -> NaN.
//   Fix: af0..af15 are 16 NAMED uint4 variables (macro-generated blocks,
//   literal chunk numbers) -> cannot be runtime-indexed -> guaranteed
//   registers. Per retry: reload asm -> vmcnt(0) asm -> sched_barrier(0)
//   -> VALU check (rule-18 ordering kept).
//   Pipeline: chunk c depends only on producers 2c/2c+1 -> validate 4
//   dwords, retry ONLY that 256 B chunk, run its 8 MFMAs immediately;
//   early chunks compute while stragglers arrive.
// Kept from R15 PASS: sentinel handshake (hist 0xFF-prefilled, fresh slab
// per step, publish = bypass stores only), wave-decoupled, bhi+blo
// LDS-resident 2-product GEMM, tbuf wave-local transpose, s==0 fast path,
// dead-man cap (sentinel survives -> NaN gates -> loud absmax fail).
// ---------------------------------------------------------------------------
__global__ __launch_bounds__(256, 1) void lstm_mfma(
    const float* __restrict__ E2, const float* __restrict__ pssm,
    const int* __restrict__ seq,
    const float* __restrict__ Wih_f, const float* __restrict__ Wih_b,
    const unsigned short* __restrict__ WhhHi, const unsigned short* __restrict__ WhhLo,
    unsigned short* __restrict__ hs16_f, unsigned short* __restrict__ hs16_b)
{
    __shared__ unsigned short bhi[4 * 16 * 64 * 8];   // W_hi B-frags, 64 KB
    __shared__ unsigned short blo[4 * 16 * 64 * 8];   // W_lo B-frags, 64 KB
    __shared__ float wpsh[4][PSSM][16];               // pssm weights, 5.25 KB
    __shared__ float wesh[20][68];                    // E2 slice, 5.3 KB
    __shared__ unsigned short tbuf[4][16][20];        // per-WAVE transpose, 2.5 KB

    const int wg    = blockIdx.x;
    const int dir   = wg >> 5;
    const int wslot = wg & 31;
    const int j0    = wslot * UPW;
    const int tid   = threadIdx.x;
    const int l     = tid & 63;
    const int q     = tid >> 6;            // wave = batch-quarter
    const int u     = l & 15;              // unit within WG (n index)
    const int kh    = l >> 4;              // quad
    const int m0    = q * 16 + kh * 4;     // base batch (+r)

    const float* Wih = dir ? Wih_b : Wih_f;
    const float* E2d = E2 + (size_t)dir * 20 * 2048;
    const unsigned short* Whi = WhhHi + (size_t)dir * 2048 * 512;
    const unsigned short* Wlo = WhhLo + (size_t)dir * 2048 * 512;
    unsigned short* hist  = dir ? hs16_b : hs16_f;    // [t][b][k] fp16

    // ---- one-time LDS fills (plain cached loads) ----
    for (int i = tid; i < 4 * 16 * 64; i += 256) {     // W_hi + W_lo B-frags
        int l2 = i & 63, c2 = (i >> 6) & 15, g2 = i >> 10;
        int row = g2 * 512 + j0 + (l2 & 15);
        size_t off = (size_t)row * 512 + c2 * 32 + (l2 >> 4) * 8;
        *(uint4*)&bhi[i * 8] = *(const uint4*)(Whi + off);
        *(uint4*)&blo[i * 8] = *(const uint4*)(Wlo + off);
    }
    for (int i = tid; i < 4 * PSSM * 16; i += 256) {   // pssm weight slice
        int uu = i & 15, rem = i >> 4;
        int k = rem % PSSM, g = rem / PSSM;
        wpsh[g][k][uu] = Wih[(size_t)(g * 512 + j0 + uu) * DIN + ED + k];
    }
    for (int i = tid; i < 20 * 64; i += 256) {         // E2 slice
        int sym = i >> 6, col = i & 63;
        wesh[sym][col] = E2d[(size_t)sym * 2048 + (col >> 4) * 512 + j0 + (col & 15)];
    }
    __syncthreads();   // last barrier: shared LDS read-only from here;
                       // tbuf is quarter-partitioned (wave-local)

    float creg[4] = {0.f, 0.f, 0.f, 0.f};

    for (int s = 0; s < L; ++s) {
        const int t     = dir ? (L - 1 - s) : s;
        const int tprev = dir ? (t + 1) : (t - 1);     // slab written at s-1

        // ---- input part (h-independent) ----
        float zin[4][4];
        int sb[4];
        #pragma unroll
        for (int r = 0; r < 4; ++r) sb[r] = seq[t * B + m0 + r];
        #pragma unroll
        for (int g = 0; g < 4; ++g)
            #pragma unroll
            for (int r = 0; r < 4; ++r)
                zin[g][r] = wesh[sb[r]][g * 16 + u];
        {
            const float* pb = pssm + (size_t)t * B * PSSM;
            #pragma unroll
            for (int k = 0; k < PSSM; ++k) {
                float p0 = pb[(m0 + 0) * PSSM + k];
                float p1 = pb[(m0 + 1) * PSSM + k];
                float p2 = pb[(m0 + 2) * PSSM + k];
                float p3 = pb[(m0 + 3) * PSSM + k];
                #pragma unroll
                for (int g = 0; g < 4; ++g) {
                    float wv = wpsh[g][k][u];
                    zin[g][0] = fmaf(p0, wv, zin[g][0]);
                    zin[g][1] = fmaf(p1, wv, zin[g][1]);
                    zin[g][2] = fmaf(p2, wv, zin[g][2]);
                    zin[g][3] = fmaf(p3, wv, zin[g][3]);
                }
            }
        }

        // ---- recurrent GEMM accumulator, C init = input part ----
        f32x4 acc[4];
        #pragma unroll
        for (int g = 0; g < 4; ++g)
            acc[g] = (f32x4){zin[g][0], zin[g][1], zin[g][2], zin[g][3]};

        if (s > 0) {
            const unsigned short* src =
                hist + (size_t)tprev * HB + (size_t)(q * 16 + u) * 512 + kh * 8;

            // 16 NAMED uint4 fragments — cannot be runtime-indexed, so the
            // allocator keeps them in VGPRs (R16's scratch hazard is
            // structurally impossible).
            uint4 af0, af1, af2, af3, af4, af5, af6, af7,
                  af8, af9, af10, af11, af12, af13, af14, af15;

#define LOAD_CHUNK(c) \
            asm volatile("global_load_dwordx4 %0, %1, off sc0 sc1" \
                         : "=&v"(af##c) : "v"(src + (c) * 32) : "memory");

            // attempt-0: issue all 16 chunk loads, single drain
            LOAD_CHUNK(0)  LOAD_CHUNK(1)  LOAD_CHUNK(2)  LOAD_CHUNK(3)
            LOAD_CHUNK(4)  LOAD_CHUNK(5)  LOAD_CHUNK(6)  LOAD_CHUNK(7)
            LOAD_CHUNK(8)  LOAD_CHUNK(9)  LOAD_CHUNK(10) LOAD_CHUNK(11)
            LOAD_CHUNK(12) LOAD_CHUNK(13) LOAD_CHUNK(14) LOAD_CHUNK(15)
            asm volatile("s_waitcnt vmcnt(0)" ::: "memory");
            __builtin_amdgcn_sched_barrier(0);

            int it = 0;

            // per chunk: validate -> retry only this 256 B chunk -> 8 MFMAs.
            // Early chunks compute while straggler chunks arrive.
#define CHUNK_STEP(c) \
            { \
                while (true) { \
                    unsigned bad = (unsigned)(af##c.x == 0xFFFFFFFFu) \
                                 | (unsigned)(af##c.y == 0xFFFFFFFFu) \
                                 | (unsigned)(af##c.z == 0xFFFFFFFFu) \
                                 | (unsigned)(af##c.w == 0xFFFFFFFFu); \
                    if (__all(bad == 0u)) break; \
                    if (++it > (1 << 17)) break; \
                    __builtin_amdgcn_s_sleep(1); \
                    LOAD_CHUNK(c) \
                    asm volatile("s_waitcnt vmcnt(0)" ::: "memory"); \
                    __builtin_amdgcn_sched_barrier(0); \
                } \
                half8 ah = *(const half8*)&af##c; \
                _Pragma("unroll") \
                for (int g = 0; g < 4; ++g) { \
                    half8 bh = *(const half8*)&bhi[((g * 16 + (c)) * 64 + l) * 8]; \
                    half8 bl = *(const half8*)&blo[((g * 16 + (c)) * 64 + l) * 8]; \
                    acc[g] = __builtin_amdgcn_mfma_f32_16x16x32_f16(ah, bh, acc[g], 0, 0, 0); \
                    acc[g] = __builtin_amdgcn_mfma_f32_16x16x32_f16(ah, bl, acc[g], 0, 0, 0); \
                } \
            }

            CHUNK_STEP(0)  CHUNK_STEP(1)  CHUNK_STEP(2)  CHUNK_STEP(3)
            CHUNK_STEP(4)  CHUNK_STEP(5)  CHUNK_STEP(6)  CHUNK_STEP(7)
            CHUNK_STEP(8)  CHUNK_STEP(9)  CHUNK_STEP(10) CHUNK_STEP(11)
            CHUNK_STEP(12) CHUNK_STEP(13) CHUNK_STEP(14) CHUNK_STEP(15)
#undef CHUNK_STEP
#undef LOAD_CHUNK
        }

        // ---- gates (in-lane), cell update, h -> wave-local transpose ----
        #pragma unroll
        for (int r = 0; r < 4; ++r) {
            float iv = acc[0][r], fv = acc[1][r], gv = acc[2][r], ov = acc[3][r];
            iv = 1.f / (1.f + __expf(-iv));
            fv = 1.f / (1.f + __expf(-fv));
            gv = fast_tanh(gv);
            ov = 1.f / (1.f + __expf(-ov));
            float cc = fv * creg[r] + iv * gv;
            creg[r] = cc;
            float hv = ov * fast_tanh(cc);
            tbuf[q][kh * 4 + r][u] = __half_as_ushort(__float2half_rn(hv));
        }
        // wave-local LDS RAW: DS ops are in-order per wave.

        // ---- publish own quarter into hist[t] (bypass stores; no drain,
        //      no flag — arrival of non-sentinel data IS the release) ----
        {
            int bq = l >> 2, g4 = (l & 3) * 4;            // 4 units per lane
            int bb = q * 16 + bq;
            unsigned v0 = *(const unsigned*)&tbuf[q][bq][g4];
            unsigned v1 = *(const unsigned*)&tbuf[q][bq][g4 + 2];
            unsigned short* hd = hist + (size_t)t * HB + bb * 512 + j0 + g4;
            asm volatile("global_store_dword %0, %1, off sc0 sc1"
                         :: "v"(hd), "v"(v0) : "memory");
            asm volatile("global_store_dword %0, %1, off sc0 sc1"
                         :: "v"(hd + 2), "v"(v1) : "memory");
        }
    }
}

// ---------------------------------------------------------------------------
// K2: logits -> softmax -> alphabet mix -> normalized sin/cos of torsions.
// h history fp16 [t][b][k]: per-lane uint4 h loads + float4 W_lin rows.
// ---------------------------------------------------------------------------
__global__ __launch_bounds__(256) void proj_softmax(
    const unsigned short* __restrict__ hsf, const unsigned short* __restrict__ hsb,
    const float* __restrict__ W_lin, const float* __restrict__ b_lin,
    const float* __restrict__ alphabet, float* __restrict__ sp, float* __restrict__ cp)
{
    const int t   = blockIdx.x;
    const int tid = threadIdx.x;
    const int b   = tid & 63;
    const int ug  = __builtin_amdgcn_readfirstlane(tid >> 6);
    constexpr int NU = 15;

    __shared__ float lg[B][LU];
    __shared__ float sa[LU][3], ca[LU][3];
    if (tid < LU) {
        for (int k = 0; k < 3; ++k) {
            float a = alphabet[tid * 3 + k];
            sa[tid][k] = __sinf(a);
            ca[tid][k] = __cosf(a);
        }
    }

    const int u0 = ug * NU;
    float acc[NU];
    #pragma unroll
    for (int i = 0; i < NU; ++i) acc[i] = b_lin[u0 + i];

    #pragma unroll
    for (int half = 0; half < 2; ++half) {
        const unsigned short* hp =
            (half ? hsb : hsf) + (size_t)t * HB + (size_t)b * H;
        for (int j8 = 0; j8 < H / 8; ++j8) {
            uint4 hv4 = *(const uint4*)(hp + j8 * 8);
            const __half* hx = (const __half*)&hv4;
            float hvv[8];
            #pragma unroll
            for (int jj = 0; jj < 8; ++jj) hvv[jj] = __half2float(hx[jj]);
            #pragma unroll
            for (int i = 0; i < NU; ++i) {
                const float* wr = W_lin + (size_t)(u0 + i) * (2 * H) + half * H + j8 * 8;
                float4 wa = *(const float4*)wr;
                float4 wb = *(const float4*)(wr + 4);
                acc[i] = fmaf(hvv[0], wa.x, acc[i]);
                acc[i] = fmaf(hvv[1], wa.y, acc[i]);
                acc[i] = fmaf(hvv[2], wa.z, acc[i]);
                acc[i] = fmaf(hvv[3], wa.w, acc[i]);
                acc[i] = fmaf(hvv[4], wb.x, acc[i]);
                acc[i] = fmaf(hvv[5], wb.y, acc[i]);
                acc[i] = fmaf(hvv[6], wb.z, acc[i]);
                acc[i] = fmaf(hvv[7], wb.w, acc[i]);
            }
        }
    }
    #pragma unroll
    for (int i = 0; i < NU; ++i) lg[b][u0 + i] = acc[i];
    __syncthreads();

    if (tid < B) {
        float m = -1e30f;
        for (int u = 0; u < LU; ++u) m = fmaxf(m, lg[tid][u]);
        float sv[3] = {0, 0, 0}, cv[3] = {0, 0, 0};
        for (int u = 0; u < LU; ++u) {
            float e = __expf(lg[tid][u] - m);
            for (int k = 0; k < 3; ++k) {
                sv[k] = fmaf(e, sa[u][k], sv[k]);
                cv[k] = fmaf(e, ca[u][k], cv[k]);
            }
        }
        for (int k = 0; k < 3; ++k) {
            float r = rsqrtf(sv[k] * sv[k] + cv[k] * cv[k]);
            sp[((size_t)t * B + tid) * 3 + k] = sv[k] * r;
            cp[((size_t)t * B + tid) * 3 + k] = cv[k] * r;
        }
    }
}

// ---------------------------------------------------------------------------
// K3: sequential NeRF extension. One wave, lane = chain.
// ---------------------------------------------------------------------------
__global__ void geometry(const float* __restrict__ sp, const float* __restrict__ cp,
                         float* __restrict__ out)
{
    const int b = threadIdx.x;
    const float Rj[3] = {132.868f, 145.801f, 152.326f};
    const float Tj[3] = {2.028f, 2.124f, 1.941f};
    float cT[3], sT[3];
    for (int j = 0; j < 3; ++j) { cT[j] = cosf(Tj[j]); sT[j] = sinf(Tj[j]); }

    for (int r = 0; r < 3; ++r)
        for (int c = 0; c < 3; ++c)
            out[((size_t)r * B + b) * 3 + c] = (r == c) ? 1.f : 0.f;

    float Ax = 1.f, Ay = 0.f, Az = 0.f;
    float Bx = 0.f, By = 1.f, Bz = 0.f;
    float Cx = 0.f, Cy = 0.f, Cz = 1.f;

    for (int t = 0; t < L; ++t) {
        for (int j = 0; j < 3; ++j) {
            float sP = sp[((size_t)t * B + b) * 3 + j];
            float cP = cp[((size_t)t * B + b) * 3 + j];
            float d0 = -Rj[j] * cT[j];
            float d1 =  Rj[j] * cP * sT[j];
            float d2 =  Rj[j] * sP * sT[j];

            float bcx = Cx - Bx, bcy = Cy - By, bcz = Cz - Bz;
            float inv = rsqrtf(bcx * bcx + bcy * bcy + bcz * bcz);
            bcx *= inv; bcy *= inv; bcz *= inv;

            float abx = Bx - Ax, aby = By - Ay, abz = Bz - Az;
            float nx = aby * bcz - abz * bcy;
            float ny = abz * bcx - abx * bcz;
            float nz = abx * bcy - aby * bcx;
            inv = rsqrtf(nx * nx + ny * ny + nz * nz);
            nx *= inv; ny *= inv; nz *= inv;

            float mx = ny * bcz - nz * bcy;
            float my = nz * bcx - nx * bcz;
            float mz = nx * bcy - ny * bcx;

            float Dx = bcx * d0 + mx * d1 + nx * d2 + Cx;
            float Dy = bcy * d0 + my * d1 + ny * d2 + Cy;
            float Dz = bcz * d0 + mz * d1 + nz * d2 + Cz;

            size_t r = 3 + 3 * (size_t)t + j;
            out[(r * B + b) * 3 + 0] = Dx;
            out[(r * B + b) * 3 + 1] = Dy;
            out[(r * B + b) * 3 + 2] = Dz;

            Ax = Bx; Ay = By; Az = Bz;
            Bx = Cx; By = Cy; Bz = Cz;
            Cx = Dx; Cy = Dy; Cz = Dz;
        }
    }
}

// ---------------------------------------------------------------------------
extern "C" void kernel_launch(void* const* d_in, const int* in_sizes, int n_in,
                              void* d_out, int out_size, void* d_ws, size_t ws_size,
                              hipStream_t stream)
{
    const int*   seq      = (const int*)  d_in[0];
    const float* pssm     = (const float*)d_in[1];
    // d_in[2] = length (all full-length)
    const float* embed    = (const float*)d_in[3];
    const float* Wih_f    = (const float*)d_in[4];
    const float* Whh_f    = (const float*)d_in[5];
    const float* bih_f    = (const float*)d_in[6];
    const float* bhh_f    = (const float*)d_in[7];
    const float* Wih_b    = (const float*)d_in[8];
    const float* Whh_b    = (const float*)d_in[9];
    const float* bih_b    = (const float*)d_in[10];
    const float* bhh_b    = (const float*)d_in[11];
    const float* W_lin    = (const float*)d_in[12];
    const float* b_lin    = (const float*)d_in[13];
    const float* alphabet = (const float*)d_in[14];
    float* out = (float*)d_out;

    // workspace layout (~136.3 MB)
    char* ws = (char*)d_ws;
    unsigned short* hs16_f = (unsigned short*)ws;                 // 64 MB [t][b][k] fp16
    unsigned short* hs16_b = (unsigned short*)(ws + 67108864);    // 64 MB
    float* E2      = (float*)(ws + 134217728);                    // 320 KB
    unsigned short* WhhHi = (unsigned short*)(ws + 134545408);    // 4 MB
    unsigned short* WhhLo = (unsigned short*)(ws + 138739712);    // 4 MB
    // sp/cp overlay E2/Whh region (dead after the LSTM kernel finishes)
    float* sp      = (float*)(ws + 134217728);                    // 768 KB
    float* cp      = (float*)(ws + 134217728 + 786432);           // 768 KB

    // sentinel-fill both hist slabs: 0xFFFFFFFF dwords are impossible as
    // valid fp16 h pairs -> "not yet written" marker for the handshake
    (void)hipMemsetAsync(ws, 0xFF, 134217728, stream);

    prep_e2<<<dim3(320), dim3(256), 0, stream>>>(Wih_f, Wih_b, bih_f, bhh_f,
                                                 bih_b, bhh_b, embed, E2);
    prep_whh<<<dim3(8192), dim3(256), 0, stream>>>(Whh_f, Whh_b, WhhHi, WhhLo);

    lstm_mfma<<<dim3(2 * NWG_DIR), dim3(256), 0, stream>>>(
        E2, pssm, seq, Wih_f, Wih_b, WhhHi, WhhLo, hs16_f, hs16_b);

    proj_softmax<<<dim3(L), dim3(256), 0, stream>>>(
        hs16_f, hs16_b, W_lin, b_lin, alphabet, sp, cp);
    geometry<<<dim3(1), dim3(64), 0, stream>>>(sp, cp, out);
}

// Round 20
// 7008.014 us; speedup vs baseline: 1.2307x; 1.2307x over previous
//
#include <hip/hip_runtime.h>
#include <hip/hip_bf16.h>
#include <hip/hip_fp16.h>
#include <math.h>

// Problem constants
constexpr int L    = 1024;
constexpr int B    = 64;
constexpr int H    = 512;
constexpr int ED   = 512;
constexpr int PSSM = 21;
constexpr int DIN  = ED + PSSM;    // 533
constexpr int LU   = 60;
constexpr int HB   = H * B;        // 32768 shorts (64 KB) per timestep slab
constexpr int NWG_DIR = 32;        // fat MFMA workgroups per direction
constexpr int UPW  = 16;           // hidden units per WG

typedef __attribute__((ext_vector_type(8))) _Float16 half8;    // MFMA fp16 frag
typedef __attribute__((ext_vector_type(4))) float f32x4;       // MFMA acc frag

__device__ __forceinline__ float fast_tanh(float x) {
    // tanh(x) = 1 - 2/(exp(2x)+1); exp overflow -> 1, underflow -> -1 (no NaN)
    // Validated in R19 pass (absmax 1024 = 1 ulp, same as libm version).
    float e = __expf(2.f * x);
    return 1.f - 2.f / (e + 1.f);
}

// ---------------------------------------------------------------------------
// P0: E2[dir][sym][col] = embed[sym] . Wih_dir[col][0:512] + bih[col]+bhh[col]
// ---------------------------------------------------------------------------
__global__ __launch_bounds__(256) void prep_e2(
    const float* __restrict__ Wih_f, const float* __restrict__ Wih_b,
    const float* __restrict__ bih_f, const float* __restrict__ bhh_f,
    const float* __restrict__ bih_b, const float* __restrict__ bhh_b,
    const float* __restrict__ embed, float* __restrict__ E2)
{
    int idx  = blockIdx.x * 256 + threadIdx.x;   // 0 .. 81919
    int col  = idx & 2047;
    int rest = idx >> 11;
    int s    = rest % 20;
    int dir  = rest / 20;
    const float* W  = dir ? Wih_b : Wih_f;
    const float* er = embed + (size_t)s * ED;
    const float* wr = W + (size_t)col * DIN;
    float a = 0.f;
    #pragma unroll 8
    for (int k = 0; k < ED; ++k) a = fmaf(er[k], wr[k], a);
    a += (dir ? bih_b : bih_f)[col] + (dir ? bhh_b : bhh_f)[col];
    E2[idx] = a;
}

// ---------------------------------------------------------------------------
// P1: split Whh into fp16 hi/lo pair (2-product split, w err ~2^-22).
// R13 PROVED single-product fp16 diverges 75x over threshold -> 2 required.
// ---------------------------------------------------------------------------
__global__ __launch_bounds__(256) void prep_whh(
    const float* __restrict__ Whh_f, const float* __restrict__ Whh_b,
    unsigned short* __restrict__ hi, unsigned short* __restrict__ lo)
{
    int idx = blockIdx.x * 256 + threadIdx.x;    // 0 .. 2*2048*512-1
    const int NPD = 2048 * 512;
    float w = (idx < NPD) ? Whh_f[idx] : Whh_b[idx - NPD];
    __half h = __float2half_rn(w);
    __half l2 = __float2half_rn(w - __half2float(h));
    hi[idx] = __half_as_ushort(h);
    lo[idx] = __half_as_ushort(l2);
}

// ---------------------------------------------------------------------------
// K1: persistent bidirectional LSTM, MFMA fp16. 64 WGs (32/dir), 1 WG/CU.
// R20 = CONSOLIDATION: R15 structure (best passing, 6.55 ms steady) +
// fast_tanh (validated in R19's pass).
//   R19 post-mortem: per-chunk retry SERIALIZES the miss path (up to 16
//   sequential RTTs/step when consumer leads producer) -> 9.6 ms. R15's
//   batched retry (16 loads in flight, ONE drain per round) is strictly
//   better -> reverted to it.
// Structure (all individually proven):
//   - sentinel handshake: hist[t][b][k] fp16, 0xFF-prefilled; fresh slab
//     per step -> no ordering constraint; publish = sc0sc1 stores only
//     (no drain/flag/atomic); consumer batch-loads its 16-chunk row and
//     retries until no dword == 0xFFFFFFFF (impossible as valid fp16 h).
//   - wave-decoupled: wave q owns batch quarter [16q,16q+16); zero
//     main-loop __syncthreads.
//   - bhi+blo LDS-resident 2-product fp16 GEMM (141 KB LDS, no streamed
//     global loads in the MFMA chain).
//   - af[16] with FULL unroll of simple loops only -> registers (R6 fix);
//     vmcnt(0)+sched_barrier(0) before VALU checks (rule 18).
//   - dead-man cap: sentinel survives -> NaN gates -> loud absmax fail.
// ---------------------------------------------------------------------------
__global__ __launch_bounds__(256, 1) void lstm_mfma(
    const float* __restrict__ E2, const float* __restrict__ pssm,
    const int* __restrict__ seq,
    const float* __restrict__ Wih_f, const float* __restrict__ Wih_b,
    const unsigned short* __restrict__ WhhHi, const unsigned short* __restrict__ WhhLo,
    unsigned short* __restrict__ hs16_f, unsigned short* __restrict__ hs16_b)
{
    __shared__ unsigned short bhi[4 * 16 * 64 * 8];   // W_hi B-frags, 64 KB
    __shared__ unsigned short blo[4 * 16 * 64 * 8];   // W_lo B-frags, 64 KB
    __shared__ float wpsh[4][PSSM][16];               // pssm weights, 5.25 KB
    __shared__ float wesh[20][68];                    // E2 slice, 5.3 KB
    __shared__ unsigned short tbuf[4][16][20];        // per-WAVE transpose, 2.5 KB

    const int wg    = blockIdx.x;
    const int dir   = wg >> 5;
    const int wslot = wg & 31;
    const int j0    = wslot * UPW;
    const int tid   = threadIdx.x;
    const int l     = tid & 63;
    const int q     = tid >> 6;            // wave = batch-quarter
    const int u     = l & 15;              // unit within WG (n index)
    const int kh    = l >> 4;              // quad
    const int m0    = q * 16 + kh * 4;     // base batch (+r)

    const float* Wih = dir ? Wih_b : Wih_f;
    const float* E2d = E2 + (size_t)dir * 20 * 2048;
    const unsigned short* Whi = WhhHi + (size_t)dir * 2048 * 512;
    const unsigned short* Wlo = WhhLo + (size_t)dir * 2048 * 512;
    unsigned short* hist  = dir ? hs16_b : hs16_f;    // [t][b][k] fp16

    // ---- one-time LDS fills (plain cached loads) ----
    for (int i = tid; i < 4 * 16 * 64; i += 256) {     // W_hi + W_lo B-frags
        int l2 = i & 63, c2 = (i >> 6) & 15, g2 = i >> 10;
        int row = g2 * 512 + j0 + (l2 & 15);
        size_t off = (size_t)row * 512 + c2 * 32 + (l2 >> 4) * 8;
        *(uint4*)&bhi[i * 8] = *(const uint4*)(Whi + off);
        *(uint4*)&blo[i * 8] = *(const uint4*)(Wlo + off);
    }
    for (int i = tid; i < 4 * PSSM * 16; i += 256) {   // pssm weight slice
        int uu = i & 15, rem = i >> 4;
        int k = rem % PSSM, g = rem / PSSM;
        wpsh[g][k][uu] = Wih[(size_t)(g * 512 + j0 + uu) * DIN + ED + k];
    }
    for (int i = tid; i < 20 * 64; i += 256) {         // E2 slice
        int sym = i >> 6, col = i & 63;
        wesh[sym][col] = E2d[(size_t)sym * 2048 + (col >> 4) * 512 + j0 + (col & 15)];
    }
    __syncthreads();   // last barrier: shared LDS read-only from here;
                       // tbuf is quarter-partitioned (wave-local)

    float creg[4] = {0.f, 0.f, 0.f, 0.f};

    for (int s = 0; s < L; ++s) {
        const int t     = dir ? (L - 1 - s) : s;
        const int tprev = dir ? (t + 1) : (t - 1);     // slab written at s-1

        // ---- input part (h-independent) ----
        float zin[4][4];
        int sb[4];
        #pragma unroll
        for (int r = 0; r < 4; ++r) sb[r] = seq[t * B + m0 + r];
        #pragma unroll
        for (int g = 0; g < 4; ++g)
            #pragma unroll
            for (int r = 0; r < 4; ++r)
                zin[g][r] = wesh[sb[r]][g * 16 + u];
        {
            const float* pb = pssm + (size_t)t * B * PSSM;
            #pragma unroll
            for (int k = 0; k < PSSM; ++k) {
                float p0 = pb[(m0 + 0) * PSSM + k];
                float p1 = pb[(m0 + 1) * PSSM + k];
                float p2 = pb[(m0 + 2) * PSSM + k];
                float p3 = pb[(m0 + 3) * PSSM + k];
                #pragma unroll
                for (int g = 0; g < 4; ++g) {
                    float wv = wpsh[g][k][u];
                    zin[g][0] = fmaf(p0, wv, zin[g][0]);
                    zin[g][1] = fmaf(p1, wv, zin[g][1]);
                    zin[g][2] = fmaf(p2, wv, zin[g][2]);
                    zin[g][3] = fmaf(p3, wv, zin[g][3]);
                }
            }
        }

        // ---- recurrent GEMM accumulator, C init = input part ----
        f32x4 acc[4];
        #pragma unroll
        for (int g = 0; g < 4; ++g)
            acc[g] = (f32x4){zin[g][0], zin[g][1], zin[g][2], zin[g][3]};

        if (s > 0) {
            // ---- sentinel poll: BATCHED — 16 loads in flight, one drain
            //      per round, check all 64 dwords; retry whole batch.
            //      (R19 proved per-chunk retry serializes the miss path.)
            uint4 af[16];
            const unsigned short* src =
                hist + (size_t)tprev * HB + (size_t)(q * 16 + u) * 512 + kh * 8;
            int it = 0;
            while (true) {
                #pragma unroll
                for (int c = 0; c < 16; ++c)
                    asm volatile("global_load_dwordx4 %0, %1, off sc0 sc1"
                                 : "=&v"(af[c]) : "v"(src + c * 32) : "memory");
                asm volatile("s_waitcnt vmcnt(0)" ::: "memory");
                __builtin_amdgcn_sched_barrier(0);
                unsigned bad = 0u;
                #pragma unroll
                for (int c = 0; c < 16; ++c) {
                    bad |= (unsigned)(af[c].x == 0xFFFFFFFFu);
                    bad |= (unsigned)(af[c].y == 0xFFFFFFFFu);
                    bad |= (unsigned)(af[c].z == 0xFFFFFFFFu);
                    bad |= (unsigned)(af[c].w == 0xFFFFFFFFu);
                }
                if (__all(bad == 0u)) break;
                __builtin_amdgcn_s_sleep(1);
                if (++it > (1 << 17)) break;
            }
            __builtin_amdgcn_sched_barrier(0);

            // ---- K=512, 16 chunks, 2 fp16 products, ALL operands
            //      register/LDS-resident. FULL unroll (constant af idx). ----
            #pragma unroll
            for (int c = 0; c < 16; ++c) {
                half8 ah = *(const half8*)&af[c];
                #pragma unroll
                for (int g = 0; g < 4; ++g) {
                    half8 bh = *(const half8*)&bhi[((g * 16 + c) * 64 + l) * 8];
                    half8 bl = *(const half8*)&blo[((g * 16 + c) * 64 + l) * 8];
                    acc[g] = __builtin_amdgcn_mfma_f32_16x16x32_f16(ah, bh, acc[g], 0, 0, 0);
                    acc[g] = __builtin_amdgcn_mfma_f32_16x16x32_f16(ah, bl, acc[g], 0, 0, 0);
                }
            }
        }

        // ---- gates (in-lane), cell update, h -> wave-local transpose ----
        #pragma unroll
        for (int r = 0; r < 4; ++r) {
            float iv = acc[0][r], fv = acc[1][r], gv = acc[2][r], ov = acc[3][r];
            iv = 1.f / (1.f + __expf(-iv));
            fv = 1.f / (1.f + __expf(-fv));
            gv = fast_tanh(gv);
            ov = 1.f / (1.f + __expf(-ov));
            float cc = fv * creg[r] + iv * gv;
            creg[r] = cc;
            float hv = ov * fast_tanh(cc);
            tbuf[q][kh * 4 + r][u] = __half_as_ushort(__float2half_rn(hv));
        }
        // wave-local LDS RAW: DS ops are in-order per wave.

        // ---- publish own quarter into hist[t] (bypass stores; no drain,
        //      no flag — arrival of non-sentinel data IS the release) ----
        {
            int bq = l >> 2, g4 = (l & 3) * 4;            // 4 units per lane
            int bb = q * 16 + bq;
            unsigned v0 = *(const unsigned*)&tbuf[q][bq][g4];
            unsigned v1 = *(const unsigned*)&tbuf[q][bq][g4 + 2];
            unsigned short* hd = hist + (size_t)t * HB + bb * 512 + j0 + g4;
            asm volatile("global_store_dword %0, %1, off sc0 sc1"
                         :: "v"(hd), "v"(v0) : "memory");
            asm volatile("global_store_dword %0, %1, off sc0 sc1"
                         :: "v"(hd + 2), "v"(v1) : "memory");
        }
    }
}

// ---------------------------------------------------------------------------
// K2: logits -> softmax -> alphabet mix -> normalized sin/cos of torsions.
// h history fp16 [t][b][k]: per-lane uint4 h loads + float4 W_lin rows.
// ---------------------------------------------------------------------------
__global__ __launch_bounds__(256) void proj_softmax(
    const unsigned short* __restrict__ hsf, const unsigned short* __restrict__ hsb,
    const float* __restrict__ W_lin, const float* __restrict__ b_lin,
    const float* __restrict__ alphabet, float* __restrict__ sp, float* __restrict__ cp)
{
    const int t   = blockIdx.x;
    const int tid = threadIdx.x;
    const int b   = tid & 63;
    const int ug  = __builtin_amdgcn_readfirstlane(tid >> 6);
    constexpr int NU = 15;

    __shared__ float lg[B][LU];
    __shared__ float sa[LU][3], ca[LU][3];
    if (tid < LU) {
        for (int k = 0; k < 3; ++k) {
            float a = alphabet[tid * 3 + k];
            sa[tid][k] = __sinf(a);
            ca[tid][k] = __cosf(a);
        }
    }

    const int u0 = ug * NU;
    float acc[NU];
    #pragma unroll
    for (int i = 0; i < NU; ++i) acc[i] = b_lin[u0 + i];

    #pragma unroll
    for (int half = 0; half < 2; ++half) {
        const unsigned short* hp =
            (half ? hsb : hsf) + (size_t)t * HB + (size_t)b * H;
        for (int j8 = 0; j8 < H / 8; ++j8) {
            uint4 hv4 = *(const uint4*)(hp + j8 * 8);
            const __half* hx = (const __half*)&hv4;
            float hvv[8];
            #pragma unroll
            for (int jj = 0; jj < 8; ++jj) hvv[jj] = __half2float(hx[jj]);
            #pragma unroll
            for (int i = 0; i < NU; ++i) {
                const float* wr = W_lin + (size_t)(u0 + i) * (2 * H) + half * H + j8 * 8;
                float4 wa = *(const float4*)wr;
                float4 wb = *(const float4*)(wr + 4);
                acc[i] = fmaf(hvv[0], wa.x, acc[i]);
                acc[i] = fmaf(hvv[1], wa.y, acc[i]);
                acc[i] = fmaf(hvv[2], wa.z, acc[i]);
                acc[i] = fmaf(hvv[3], wa.w, acc[i]);
                acc[i] = fmaf(hvv[4], wb.x, acc[i]);
                acc[i] = fmaf(hvv[5], wb.y, acc[i]);
                acc[i] = fmaf(hvv[6], wb.z, acc[i]);
                acc[i] = fmaf(hvv[7], wb.w, acc[i]);
            }
        }
    }
    #pragma unroll
    for (int i = 0; i < NU; ++i) lg[b][u0 + i] = acc[i];
    __syncthreads();

    if (tid < B) {
        float m = -1e30f;
        for (int u = 0; u < LU; ++u) m = fmaxf(m, lg[tid][u]);
        float sv[3] = {0, 0, 0}, cv[3] = {0, 0, 0};
        for (int u = 0; u < LU; ++u) {
            float e = __expf(lg[tid][u] - m);
            for (int k = 0; k < 3; ++k) {
                sv[k] = fmaf(e, sa[u][k], sv[k]);
                cv[k] = fmaf(e, ca[u][k], cv[k]);
            }
        }
        for (int k = 0; k < 3; ++k) {
            float r = rsqrtf(sv[k] * sv[k] + cv[k] * cv[k]);
            sp[((size_t)t * B + tid) * 3 + k] = sv[k] * r;
            cp[((size_t)t * B + tid) * 3 + k] = cv[k] * r;
        }
    }
}

// ---------------------------------------------------------------------------
// K3: sequential NeRF extension. One wave, lane = chain.
// ---------------------------------------------------------------------------
__global__ void geometry(const float* __restrict__ sp, const float* __restrict__ cp,
                         float* __restrict__ out)
{
    const int b = threadIdx.x;
    const float Rj[3] = {132.868f, 145.801f, 152.326f};
    const float Tj[3] = {2.028f, 2.124f, 1.941f};
    float cT[3], sT[3];
    for (int j = 0; j < 3; ++j) { cT[j] = cosf(Tj[j]); sT[j] = sinf(Tj[j]); }

    for (int r = 0; r < 3; ++r)
        for (int c = 0; c < 3; ++c)
            out[((size_t)r * B + b) * 3 + c] = (r == c) ? 1.f : 0.f;

    float Ax = 1.f, Ay = 0.f, Az = 0.f;
    float Bx = 0.f, By = 1.f, Bz = 0.f;
    float Cx = 0.f, Cy = 0.f, Cz = 1.f;

    for (int t = 0; t < L; ++t) {
        for (int j = 0; j < 3; ++j) {
            float sP = sp[((size_t)t * B + b) * 3 + j];
            float cP = cp[((size_t)t * B + b) * 3 + j];
            float d0 = -Rj[j] * cT[j];
            float d1 =  Rj[j] * cP * sT[j];
            float d2 =  Rj[j] * sP * sT[j];

            float bcx = Cx - Bx, bcy = Cy - By, bcz = Cz - Bz;
            float inv = rsqrtf(bcx * bcx + bcy * bcy + bcz * bcz);
            bcx *= inv; bcy *= inv; bcz *= inv;

            float abx = Bx - Ax, aby = By - Ay, abz = Bz - Az;
            float nx = aby * bcz - abz * bcy;
            float ny = abz * bcx - abx * bcz;
            float nz = abx * bcy - aby * bcx;
            inv = rsqrtf(nx * nx + ny * ny + nz * nz);
            nx *= inv; ny *= inv; nz *= inv;

            float mx = ny * bcz - nz * bcy;
            float my = nz * bcx - nx * bcz;
            float mz = nx * bcy - ny * bcx;

            float Dx = bcx * d0 + mx * d1 + nx * d2 + Cx;
            float Dy = bcy * d0 + my * d1 + ny * d2 + Cy;
            float Dz = bcz * d0 + mz * d1 + nz * d2 + Cz;

            size_t r = 3 + 3 * (size_t)t + j;
            out[(r * B + b) * 3 + 0] = Dx;
            out[(r * B + b) * 3 + 1] = Dy;
            out[(r * B + b) * 3 + 2] = Dz;

            Ax = Bx; Ay = By; Az = Bz;
            Bx = Cx; By = Cy; Bz = Cz;
            Cx = Dx; Cy = Dy; Cz = Dz;
        }
    }
}

// ---------------------------------------------------------------------------
extern "C" void kernel_launch(void* const* d_in, const int* in_sizes, int n_in,
                              void* d_out, int out_size, void* d_ws, size_t ws_size,
                              hipStream_t stream)
{
    const int*   seq      = (const int*)  d_in[0];
    const float* pssm     = (const float*)d_in[1];
    // d_in[2] = length (all full-length)
    const float* embed    = (const float*)d_in[3];
    const float* Wih_f    = (const float*)d_in[4];
    const float* Whh_f    = (const float*)d_in[5];
    const float* bih_f    = (const float*)d_in[6];
    const float* bhh_f    = (const float*)d_in[7];
    const float* Wih_b    = (const float*)d_in[8];
    const float* Whh_b    = (const float*)d_in[9];
    const float* bih_b    = (const float*)d_in[10];
    const float* bhh_b    = (const float*)d_in[11];
    const float* W_lin    = (const float*)d_in[12];
    const float* b_lin    = (const float*)d_in[13];
    const float* alphabet = (const float*)d_in[14];
    float* out = (float*)d_out;

    // workspace layout (~136.3 MB)
    char* ws = (char*)d_ws;
    unsigned short* hs16_f = (unsigned short*)ws;                 // 64 MB [t][b][k] fp16
    unsigned short* hs16_b = (unsigned short*)(ws + 67108864);    // 64 MB
    float* E2      = (float*)(ws + 134217728);                    // 320 KB
    unsigned short* WhhHi = (unsigned short*)(ws + 134545408);    // 4 MB
    unsigned short* WhhLo = (unsigned short*)(ws + 138739712);    // 4 MB
    // sp/cp overlay E2/Whh region (dead after the LSTM kernel finishes)
    float* sp      = (float*)(ws + 134217728);                    // 768 KB
    float* cp      = (float*)(ws + 134217728 + 786432);           // 768 KB

    // sentinel-fill both hist slabs: 0xFFFFFFFF dwords are impossible as
    // valid fp16 h pairs -> "not yet written" marker for the handshake
    (void)hipMemsetAsync(ws, 0xFF, 134217728, stream);

    prep_e2<<<dim3(320), dim3(256), 0, stream>>>(Wih_f, Wih_b, bih_f, bhh_f,
                                                 bih_b, bhh_b, embed, E2);
    prep_whh<<<dim3(8192), dim3(256), 0, stream>>>(Whh_f, Whh_b, WhhHi, WhhLo);

    lstm_mfma<<<dim3(2 * NWG_DIR), dim3(256), 0, stream>>>(
        E2, pssm, seq, Wih_f, Wih_b, WhhHi, WhhLo, hs16_f, hs16_b);

    proj_softmax<<<dim3(L), dim3(256), 0, stream>>>(
        hs16_f, hs16_b, W_lin, b_lin, alphabet, sp, cp);
    geometry<<<dim3(1), dim3(64), 0, stream>>>(sp, cp, out);
}